// Round 1
// baseline (138.956 us; speedup 1.0000x reference)
//
#include <hip/hip_runtime.h>

#define B_Q   8
#define DB    128
#define R_REF 4096
#define S_EDGE 32768
#define NSEG  1024
#define DBITS 1024
#define OUTD  512

typedef __bf16 bf16_t;
typedef bf16_t bf16x8 __attribute__((ext_vector_type(8)));
typedef float  f32x4  __attribute__((ext_vector_type(4)));

__device__ inline unsigned short f2bf(float f){
  unsigned int u = __builtin_bit_cast(unsigned int, f);
  u = (u + 0x7fffu + ((u >> 16) & 1u)) >> 16;
  return (unsigned short)u;
}

// Transpose+convert W (DBITS x OUTD f32, row-major) -> WT (OUTD x DBITS bf16)
__global__ __launch_bounds__(256) void k_wconv(const float* __restrict__ W,
                                               unsigned short* __restrict__ WT){
  int t = blockIdx.x * 256 + threadIdx.x;      // t < OUTD*DBITS
  int o = t >> 10, k = t & 1023;
  WT[t] = f2bf(W[k * OUTD + o]);
}

// dists[b][r] = popc(Q&refs)/popc(Qok&okpos), one wave per (b,r)
__global__ __launch_bounds__(256) void k_dist(const int* __restrict__ Q, const int* __restrict__ Qok,
                                              const int* __restrict__ refs, const int* __restrict__ okpos,
                                              float* __restrict__ dists){
  int pair = blockIdx.x * 4 + (threadIdx.x >> 6);   // b*R + r
  int l = threadIdx.x & 63;
  int b = pair >> 12;
  int r = pair & 4095;
  int q0 = Q[b*DB + l],    q1 = Q[b*DB + 64 + l];
  int a0 = Qok[b*DB + l],  a1 = Qok[b*DB + 64 + l];
  int f0 = refs[r*DB + l], f1 = refs[r*DB + 64 + l];
  int p0 = okpos[r*DB + l],p1 = okpos[r*DB + 64 + l];
  int m = __popc(q0 & f0) + __popc(q1 & f1);
  int o = __popc(a0 & p0) + __popc(a1 & p1);
  int v = m | (o << 16);
  #pragma unroll
  for (int off = 32; off; off >>= 1) v += __shfl_down(v, off);
  if (l == 0) dists[pair] = (float)(v & 0xffff) / (float)(v >> 16);
}

// One wave per (b, seg): binary-search edge range, softmax, accumulate V row (bf16)
__global__ __launch_bounds__(64) void k_seg(const float* __restrict__ dists,
                                            const int* __restrict__ ref2seg,
                                            const int* __restrict__ segments,
                                            const int* __restrict__ refs,
                                            unsigned short* __restrict__ V){
  int n = blockIdx.x, b = blockIdx.y;
  int l = threadIdx.x;

  int lo = 0, hi = S_EDGE;
  while (lo < hi){ int mid = (lo + hi) >> 1; if (segments[mid] < n) lo = mid + 1; else hi = mid; }
  int start = lo;
  hi = S_EDGE;
  while (lo < hi){ int mid = (lo + hi) >> 1; if (segments[mid] < n + 1) lo = mid + 1; else hi = mid; }
  int end = lo;

  unsigned short* vrow = V + ((size_t)(b * NSEG + n)) * DBITS + l * 16;

  if (start >= end){
    uint4 z = {0,0,0,0};
    *(uint4*)vrow = z; *(uint4*)(vrow + 8) = z;
    return;
  }

  const float* db = dists + b * R_REF;

  float mx = -1e30f;
  for (int s = start + l; s < end; s += 64) mx = fmaxf(mx, db[ref2seg[s]]);
  #pragma unroll
  for (int off = 32; off; off >>= 1) mx = fmaxf(mx, __shfl_xor(mx, off));

  float sum = 0.f;
  for (int s = start + l; s < end; s += 64) sum += __expf(db[ref2seg[s]] - mx);
  #pragma unroll
  for (int off = 32; off; off >>= 1) sum += __shfl_xor(sum, off);
  float inv = 1.0f / sum;

  float acc[16];
  #pragma unroll
  for (int i = 0; i < 16; ++i) acc[i] = 0.f;

  for (int s = start; s < end; ++s){
    int r = ref2seg[s];                       // wave-uniform
    float sc = __expf(db[r] - mx) * inv;
    int2 by = *(const int2*)(refs + r*DB + 2*l);   // bytes 2l, 2l+1 of row r
    #pragma unroll
    for (int i = 0; i < 8; ++i) acc[i]     += ((by.x >> (7 - i)) & 1) ? sc : 0.f;
    #pragma unroll
    for (int i = 0; i < 8; ++i) acc[8 + i] += ((by.y >> (7 - i)) & 1) ? sc : 0.f;
  }

  uint4 o0, o1;
  o0.x = (unsigned)f2bf(acc[0])  | ((unsigned)f2bf(acc[1])  << 16);
  o0.y = (unsigned)f2bf(acc[2])  | ((unsigned)f2bf(acc[3])  << 16);
  o0.z = (unsigned)f2bf(acc[4])  | ((unsigned)f2bf(acc[5])  << 16);
  o0.w = (unsigned)f2bf(acc[6])  | ((unsigned)f2bf(acc[7])  << 16);
  o1.x = (unsigned)f2bf(acc[8])  | ((unsigned)f2bf(acc[9])  << 16);
  o1.y = (unsigned)f2bf(acc[10]) | ((unsigned)f2bf(acc[11]) << 16);
  o1.z = (unsigned)f2bf(acc[12]) | ((unsigned)f2bf(acc[13]) << 16);
  o1.w = (unsigned)f2bf(acc[14]) | ((unsigned)f2bf(acc[15]) << 16);
  *(uint4*)vrow = o0;
  *(uint4*)(vrow + 8) = o1;
}

// out[8192x512] = V[8192x1024] * W[1024x512] + b, MFMA 16x16x32 bf16, 64x64 tiles
__global__ __launch_bounds__(256) void k_gemm(const unsigned short* __restrict__ V,
                                              const unsigned short* __restrict__ WT,
                                              const float* __restrict__ bo,
                                              float* __restrict__ out){
  int tm = blockIdx.x * 64, tn = blockIdx.y * 64;
  int w = threadIdx.x >> 6, l = threadIdx.x & 63;
  int lrow = l & 15;
  int koff = (l >> 4) * 8;

  const unsigned short* Ap  = V  + (size_t)(tm + w*16 + lrow) * DBITS + koff;
  const unsigned short* Bp0 = WT + (size_t)(tn + lrow) * DBITS + koff;

  f32x4 acc[4] = {};

  for (int k0 = 0; k0 < DBITS; k0 += 32){
    bf16x8 a = __builtin_bit_cast(bf16x8, *(const uint4*)(Ap + k0));
    #pragma unroll
    for (int nt = 0; nt < 4; ++nt){
      bf16x8 bb = __builtin_bit_cast(bf16x8, *(const uint4*)(Bp0 + (size_t)nt*16*DBITS + k0));
      acc[nt] = __builtin_amdgcn_mfma_f32_16x16x32_bf16(a, bb, acc[nt], 0, 0, 0);
    }
  }

  int crow = tm + w*16 + (l >> 4) * 4;
  #pragma unroll
  for (int nt = 0; nt < 4; ++nt){
    int col = tn + nt*16 + lrow;
    float bias = bo[col];
    #pragma unroll
    for (int q = 0; q < 4; ++q)
      out[(size_t)(crow + q) * OUTD + col] = acc[nt][q] + bias;
  }
}

extern "C" void kernel_launch(void* const* d_in, const int* in_sizes, int n_in,
                              void* d_out, int out_size, void* d_ws, size_t ws_size,
                              hipStream_t stream) {
  const int*   Q        = (const int*)d_in[0];
  const int*   Qok      = (const int*)d_in[1];
  const int*   refs     = (const int*)d_in[2];
  const int*   okpos    = (const int*)d_in[3];
  const int*   ref2seg  = (const int*)d_in[4];
  const int*   segments = (const int*)d_in[5];
  const float* W        = (const float*)d_in[7];
  const float* bo       = (const float*)d_in[8];
  float* out = (float*)d_out;

  char* ws = (char*)d_ws;
  unsigned short* WT    = (unsigned short*)ws;                          // 1 MB
  float*          dists = (float*)(ws + (1u<<20));                      // 128 KB
  unsigned short* V     = (unsigned short*)(ws + (1u<<20) + (128u<<10)); // 16 MB

  k_wconv<<<(OUTD*DBITS)/256, 256, 0, stream>>>(W, WT);
  k_dist <<<(B_Q*R_REF)/4, 256, 0, stream>>>(Q, Qok, refs, okpos, dists);
  k_seg  <<<dim3(NSEG, B_Q), 64, 0, stream>>>(dists, ref2seg, segments, refs, V);
  k_gemm <<<dim3(8192/64, OUTD/64), 256, 0, stream>>>(V, WT, bo, out);
}

// Round 2
// 84.443 us; speedup vs baseline: 1.6456x; 1.6456x over previous
//
#include <hip/hip_runtime.h>

#define B_Q   8
#define DB    128
#define R_REF 4096
#define S_EDGE 32768
#define NSEG  1024
#define DBITS 1024
#define OUTD  512

#define BM 128
#define BN 64
#define BK 64

typedef __bf16 bf16_t;
typedef bf16_t bf16x8 __attribute__((ext_vector_type(8)));
typedef float  f32x4  __attribute__((ext_vector_type(4)));
typedef unsigned int u32;

__device__ inline unsigned short f2bf(float f){
  unsigned int u = __builtin_bit_cast(unsigned int, f);
  u = (u + 0x7fffu + ((u >> 16) & 1u)) >> 16;
  return (unsigned short)u;
}

__device__ __forceinline__ void gl_lds16(const unsigned short* g, unsigned short* l){
  __builtin_amdgcn_global_load_lds((const __attribute__((address_space(1))) u32*)g,
                                   (__attribute__((address_space(3))) u32*)l, 16, 0, 0);
}

// Transpose+convert W (DBITS x OUTD f32, row-major) -> WT (OUTD x DBITS bf16)
__global__ __launch_bounds__(256) void k_wconv(const float* __restrict__ W,
                                               unsigned short* __restrict__ WT){
  int t = blockIdx.x * 256 + threadIdx.x;      // t < OUTD*DBITS
  int o = t >> 10, k = t & 1023;
  WT[t] = f2bf(W[k * OUTD + o]);
}

// dists[b][r] = popc(Q&refs)/popc(Qok&okpos), one wave per (b,r)
__global__ __launch_bounds__(256) void k_dist(const int* __restrict__ Q, const int* __restrict__ Qok,
                                              const int* __restrict__ refs, const int* __restrict__ okpos,
                                              float* __restrict__ dists){
  int pair = blockIdx.x * 4 + (threadIdx.x >> 6);   // b*R + r
  int l = threadIdx.x & 63;
  int b = pair >> 12;
  int r = pair & 4095;
  int q0 = Q[b*DB + l],    q1 = Q[b*DB + 64 + l];
  int a0 = Qok[b*DB + l],  a1 = Qok[b*DB + 64 + l];
  int f0 = refs[r*DB + l], f1 = refs[r*DB + 64 + l];
  int p0 = okpos[r*DB + l],p1 = okpos[r*DB + 64 + l];
  int m = __popc(q0 & f0) + __popc(q1 & f1);
  int o = __popc(a0 & p0) + __popc(a1 & p1);
  int v = m | (o << 16);
  #pragma unroll
  for (int off = 32; off; off >>= 1) v += __shfl_down(v, off);
  if (l == 0) dists[pair] = (float)(v & 0xffff) / (float)(v >> 16);
}

// One wave per (b, seg), 4 segs per block: softmax over edge range, accumulate V row (bf16)
__global__ __launch_bounds__(256) void k_seg(const float* __restrict__ dists,
                                             const int* __restrict__ ref2seg,
                                             const int* __restrict__ segments,
                                             const int* __restrict__ refs,
                                             unsigned short* __restrict__ V){
  int w = threadIdx.x >> 6, l = threadIdx.x & 63;
  int n = blockIdx.x * 4 + w;
  int b = blockIdx.y;

  // lanes even search lower_bound(n), lanes odd search lower_bound(n+1): 15 fixed iters
  int tgt = n + (l & 1);
  int lo = 0, hi = S_EDGE;
  #pragma unroll 1
  while (lo < hi){ int mid = (lo + hi) >> 1; if (segments[mid] < tgt) lo = mid + 1; else hi = mid; }
  int start = __shfl(lo, 0);
  int end   = __shfl(lo, 1);

  unsigned short* vrow = V + ((size_t)(b * NSEG + n)) * DBITS + l * 16;

  if (start >= end){
    uint4 z = {0,0,0,0};
    *(uint4*)vrow = z; *(uint4*)(vrow + 8) = z;
    return;
  }

  const float* db = dists + b * R_REF;

  float mx = -1e30f;
  for (int s = start + l; s < end; s += 64) mx = fmaxf(mx, db[ref2seg[s]]);
  #pragma unroll
  for (int off = 32; off; off >>= 1) mx = fmaxf(mx, __shfl_xor(mx, off));

  float sum = 0.f;
  for (int s = start + l; s < end; s += 64) sum += __expf(db[ref2seg[s]] - mx);
  #pragma unroll
  for (int off = 32; off; off >>= 1) sum += __shfl_xor(sum, off);
  float inv = 1.0f / sum;

  float acc[16];
  #pragma unroll
  for (int i = 0; i < 16; ++i) acc[i] = 0.f;

  for (int s = start; s < end; ++s){
    int r = ref2seg[s];                       // wave-uniform
    float sc = __expf(db[r] - mx) * inv;
    int2 by = *(const int2*)(refs + r*DB + 2*l);   // bytes 2l, 2l+1 of row r
    #pragma unroll
    for (int i = 0; i < 8; ++i) acc[i]     += ((by.x >> (7 - i)) & 1) ? sc : 0.f;
    #pragma unroll
    for (int i = 0; i < 8; ++i) acc[8 + i] += ((by.y >> (7 - i)) & 1) ? sc : 0.f;
  }

  uint4 o0, o1;
  o0.x = (unsigned)f2bf(acc[0])  | ((unsigned)f2bf(acc[1])  << 16);
  o0.y = (unsigned)f2bf(acc[2])  | ((unsigned)f2bf(acc[3])  << 16);
  o0.z = (unsigned)f2bf(acc[4])  | ((unsigned)f2bf(acc[5])  << 16);
  o0.w = (unsigned)f2bf(acc[6])  | ((unsigned)f2bf(acc[7])  << 16);
  o1.x = (unsigned)f2bf(acc[8])  | ((unsigned)f2bf(acc[9])  << 16);
  o1.y = (unsigned)f2bf(acc[10]) | ((unsigned)f2bf(acc[11]) << 16);
  o1.z = (unsigned)f2bf(acc[12]) | ((unsigned)f2bf(acc[13]) << 16);
  o1.w = (unsigned)f2bf(acc[14]) | ((unsigned)f2bf(acc[15]) << 16);
  *(uint4*)vrow = o0;
  *(uint4*)(vrow + 8) = o1;
}

// out[8192x512] = V[8192x1024] * WT^T + b. LDS-staged MFMA GEMM, m97 structure.
// BM=128 BN=64 BK=64, 4 waves (2x2), wave tile 64x32 (4x2 frags), grid 64x8=512 blocks (2/CU)
__global__ __launch_bounds__(256) void k_gemm(const unsigned short* __restrict__ V,
                                              const unsigned short* __restrict__ WT,
                                              const float* __restrict__ bo,
                                              float* __restrict__ out){
  __shared__ unsigned short As[BM * BK];   // 16 KB, row-major [128][64]
  __shared__ unsigned short Bs[BN * BK];   // 8 KB,  row-major [64][64] (row = out col)
  const int tid = threadIdx.x;
  const int w = tid >> 6, l = tid & 63;
  const int tm = blockIdx.x * BM, tn = blockIdx.y * BN;
  const int wm = (w & 1) * 64, wn = (w >> 1) * 32;
  const int lr = l & 15, kq = l >> 4;

  // staging: 16B chunk per thread per round; chunk index = tid + rd*256
  const unsigned short* gA = V  + (size_t)(tm + (tid >> 3)) * DBITS + (tid & 7) * 8;
  const unsigned short* gB = WT + (size_t)(tn + (tid >> 3)) * DBITS + (tid & 7) * 8;
  unsigned short* lA = As + w * 512;   // wave-uniform LDS base (+rd*2048)
  unsigned short* lB = Bs + w * 512;

  f32x4 acc[4][2] = {};

  for (int k0 = 0; k0 < DBITS; k0 += BK){
    __syncthreads();                           // readers of previous tile done
    #pragma unroll
    for (int rd = 0; rd < 4; ++rd)             // A: 128 rows = 4 rounds of 32
      gl_lds16(gA + (size_t)rd * 32 * DBITS + k0, lA + rd * 2048);
    #pragma unroll
    for (int rd = 0; rd < 2; ++rd)             // B: 64 rows = 2 rounds of 32
      gl_lds16(gB + (size_t)rd * 32 * DBITS + k0, lB + rd * 2048);
    __syncthreads();                           // vmcnt(0) drain + barrier

    #pragma unroll
    for (int kk = 0; kk < 2; ++kk){
      bf16x8 af[4], bf[2];
      #pragma unroll
      for (int m = 0; m < 4; ++m)
        af[m] = __builtin_bit_cast(bf16x8, *(const uint4*)(As + (wm + m*16 + lr)*BK + kk*32 + kq*8));
      #pragma unroll
      for (int n = 0; n < 2; ++n)
        bf[n] = __builtin_bit_cast(bf16x8, *(const uint4*)(Bs + (wn + n*16 + lr)*BK + kk*32 + kq*8));
      #pragma unroll
      for (int m = 0; m < 4; ++m)
        #pragma unroll
        for (int n = 0; n < 2; ++n)
          acc[m][n] = __builtin_amdgcn_mfma_f32_16x16x32_bf16(af[m], bf[n], acc[m][n], 0, 0, 0);
    }
  }

  #pragma unroll
  for (int n = 0; n < 2; ++n){
    const int col = tn + wn + n*16 + lr;
    const float bias = bo[col];
    #pragma unroll
    for (int m = 0; m < 4; ++m){
      const int row = tm + wm + m*16 + kq*4;
      #pragma unroll
      for (int q = 0; q < 4; ++q)
        out[(size_t)(row + q) * OUTD + col] = acc[m][n][q] + bias;
    }
  }
}

extern "C" void kernel_launch(void* const* d_in, const int* in_sizes, int n_in,
                              void* d_out, int out_size, void* d_ws, size_t ws_size,
                              hipStream_t stream) {
  const int*   Q        = (const int*)d_in[0];
  const int*   Qok      = (const int*)d_in[1];
  const int*   refs     = (const int*)d_in[2];
  const int*   okpos    = (const int*)d_in[3];
  const int*   ref2seg  = (const int*)d_in[4];
  const int*   segments = (const int*)d_in[5];
  const float* W        = (const float*)d_in[7];
  const float* bo       = (const float*)d_in[8];
  float* out = (float*)d_out;

  char* ws = (char*)d_ws;
  unsigned short* WT    = (unsigned short*)ws;                           // 1 MB
  float*          dists = (float*)(ws + (1u<<20));                       // 128 KB
  unsigned short* V     = (unsigned short*)(ws + (1u<<20) + (128u<<10)); // 16 MB

  k_wconv<<<(OUTD*DBITS)/256, 256, 0, stream>>>(W, WT);
  k_dist <<<(B_Q*R_REF)/4, 256, 0, stream>>>(Q, Qok, refs, okpos, dists);
  k_seg  <<<dim3(NSEG/4, B_Q), 256, 0, stream>>>(dists, ref2seg, segments, refs, V);
  k_gemm <<<dim3(8192/BM, OUTD/BN), 256, 0, stream>>>(V, WT, bo, out);
}

// Round 3
// 66.929 us; speedup vs baseline: 2.0762x; 1.2617x over previous
//
#include <hip/hip_runtime.h>

#define B_Q   8
#define DB    128
#define R_REF 4096
#define S_EDGE 32768
#define NSEG  1024
#define DBITS 1024
#define OUTD  512

typedef __bf16 bf16_t;
typedef bf16_t bf16x8 __attribute__((ext_vector_type(8)));
typedef float  f32x4  __attribute__((ext_vector_type(4)));
typedef unsigned int u32;

__device__ inline unsigned short f2bf(float f){
  unsigned int u = __builtin_bit_cast(unsigned int, f);
  u = (u + 0x7fffu + ((u >> 16) & 1u)) >> 16;
  return (unsigned short)u;
}

__device__ __forceinline__ void gl_lds16(const unsigned short* g, unsigned short* l){
  __builtin_amdgcn_global_load_lds((const __attribute__((address_space(1))) u32*)g,
                                   (__attribute__((address_space(3))) u32*)l, 16, 0, 0);
}

// W (DBITS x OUTD f32) -> WT (OUTD x DBITS bf16), transposed
__global__ __launch_bounds__(256) void k_wconv(const float* __restrict__ W,
                                               unsigned short* __restrict__ WT){
  int t = blockIdx.x * 256 + threadIdx.x;
  int o = t >> 10, k = t & 1023;
  WT[t] = f2bf(W[k * OUTD + o]);
}

// refs (R x 128 bytes, widened int32) -> Rb (R x 1024 bf16 of 0/1), unpackbits big-endian
__global__ __launch_bounds__(256) void k_unpack(const int* __restrict__ refs,
                                                unsigned short* __restrict__ Rb){
  int t = blockIdx.x * 256 + threadIdx.x;   // 65536 threads, 8 bytes each
  const int* p = refs + t * 8;
  uint4 o[8];
  u32* w = (u32*)o;
  #pragma unroll
  for (int j = 0; j < 8; ++j){
    u32 v = (u32)p[j];
    #pragma unroll
    for (int i2 = 0; i2 < 4; ++i2){
      u32 b0 = (v >> (7 - 2*i2)) & 1u;
      u32 b1 = (v >> (6 - 2*i2)) & 1u;
      w[j*4 + i2] = b0 * 0x3F80u | ((b1 * 0x3F80u) << 16);
    }
  }
  uint4* dst = (uint4*)(Rb + (size_t)t * 64);
  #pragma unroll
  for (int j = 0; j < 8; ++j) dst[j] = o[j];
}

// dists[b][r] = popc(Q&refs)/popc(Qok&okpos), one wave per (b,r)
__global__ __launch_bounds__(256) void k_dist(const int* __restrict__ Q, const int* __restrict__ Qok,
                                              const int* __restrict__ refs, const int* __restrict__ okpos,
                                              float* __restrict__ dists){
  int pair = blockIdx.x * 4 + (threadIdx.x >> 6);
  int l = threadIdx.x & 63;
  int b = pair >> 12;
  int r = pair & 4095;
  int q0 = Q[b*DB + l],    q1 = Q[b*DB + 64 + l];
  int a0 = Qok[b*DB + l],  a1 = Qok[b*DB + 64 + l];
  int f0 = refs[r*DB + l], f1 = refs[r*DB + 64 + l];
  int p0 = okpos[r*DB + l],p1 = okpos[r*DB + 64 + l];
  int m = __popc(q0 & f0) + __popc(q1 & f1);
  int o = __popc(a0 & p0) + __popc(a1 & p1);
  int v = m | (o << 16);
  #pragma unroll
  for (int off = 32; off; off >>= 1) v += __shfl_down(v, off);
  if (l == 0) dists[pair] = (float)(v & 0xffff) / (float)(v >> 16);
}

// segstart[n] = lower_bound(segments, n); segstart[NSEG] = S
__global__ __launch_bounds__(256) void k_bounds(const int* __restrict__ segments,
                                                int* __restrict__ segstart){
  int n = blockIdx.x * 256 + threadIdx.x;
  int lo = 0, hi = S_EDGE;
  #pragma unroll 1
  while (lo < hi){ int mid = (lo + hi) >> 1; if (segments[mid] < n) lo = mid + 1; else hi = mid; }
  segstart[n] = lo;
  if (n == 0) segstart[NSEG] = S_EDGE;
}

// U[4096][512] bf16 = Rb[4096][1024] @ WT^T. BM=BN=BK=64, 4 waves 2x2, grid 64x8
__global__ __launch_bounds__(256) void k_ugemm(const unsigned short* __restrict__ Rb,
                                               const unsigned short* __restrict__ WT,
                                               unsigned short* __restrict__ U){
  __shared__ unsigned short As[64 * 64];
  __shared__ unsigned short Bs[64 * 64];
  const int tid = threadIdx.x;
  const int w = tid >> 6, l = tid & 63;
  const int tm = blockIdx.x * 64, tn = blockIdx.y * 64;
  const int wm = (w & 1) * 32, wn = (w >> 1) * 32;
  const int lr = l & 15, kq = l >> 4;

  const unsigned short* gA = Rb + (size_t)(tm + (tid >> 3)) * DBITS + (tid & 7) * 8;
  const unsigned short* gB = WT + (size_t)(tn + (tid >> 3)) * DBITS + (tid & 7) * 8;
  unsigned short* lA = As + w * 512;
  unsigned short* lB = Bs + w * 512;

  f32x4 acc[2][2] = {};

  for (int k0 = 0; k0 < DBITS; k0 += 64){
    __syncthreads();
    gl_lds16(gA + k0, lA);
    gl_lds16(gA + (size_t)32 * DBITS + k0, lA + 2048);
    gl_lds16(gB + k0, lB);
    gl_lds16(gB + (size_t)32 * DBITS + k0, lB + 2048);
    __syncthreads();

    #pragma unroll
    for (int kk = 0; kk < 2; ++kk){
      bf16x8 af[2], bfr[2];
      #pragma unroll
      for (int m = 0; m < 2; ++m)
        af[m] = __builtin_bit_cast(bf16x8, *(const uint4*)(As + (wm + m*16 + lr)*64 + kk*32 + kq*8));
      #pragma unroll
      for (int n = 0; n < 2; ++n)
        bfr[n] = __builtin_bit_cast(bf16x8, *(const uint4*)(Bs + (wn + n*16 + lr)*64 + kk*32 + kq*8));
      #pragma unroll
      for (int m = 0; m < 2; ++m)
        #pragma unroll
        for (int n = 0; n < 2; ++n)
          acc[m][n] = __builtin_amdgcn_mfma_f32_16x16x32_bf16(af[m], bfr[n], acc[m][n], 0, 0, 0);
    }
  }

  #pragma unroll
  for (int n = 0; n < 2; ++n){
    #pragma unroll
    for (int m = 0; m < 2; ++m){
      int row = tm + wm + m*16 + kq*4;
      int col = tn + wn + n*16 + lr;
      #pragma unroll
      for (int q = 0; q < 4; ++q)
        U[(size_t)(row + q) * OUTD + col] = f2bf(acc[m][n][q]);
    }
  }
}

__device__ __forceinline__ void fma8(uint4 u, float sc, float* a){
  u32 uu[4] = {u.x, u.y, u.z, u.w};
  #pragma unroll
  for (int k = 0; k < 4; ++k){
    float lo = __builtin_bit_cast(float, uu[k] << 16);
    float hi = __builtin_bit_cast(float, uu[k] & 0xffff0000u);
    a[2*k]   += sc * lo;
    a[2*k+1] += sc * hi;
  }
}

// one block per segment; 8 b x 32 threads x 16 cols; out[b,n,:] = sum_e score*U[r,:] + bias
__global__ __launch_bounds__(256) void k_scat(const float* __restrict__ dists,
                                              const int* __restrict__ ref2seg,
                                              const int* __restrict__ segstart,
                                              const unsigned short* __restrict__ U,
                                              const float* __restrict__ bo,
                                              float* __restrict__ out){
  const int n = blockIdx.x;
  const int t = threadIdx.x;
  const int b = t >> 5;
  const int c = (t & 31) * 16;
  const int start = segstart[n], end = segstart[n + 1];
  const float* db = dists + b * R_REF;

  // online softmax stats over this (b, n)'s edges, strided across the 32-lane group
  float m = -1e30f, s = 0.f;
  for (int e = start + (t & 31); e < end; e += 32){
    float d = db[ref2seg[e]];
    float mn = fmaxf(m, d);
    s = s * __expf(m - mn) + __expf(d - mn);
    m = mn;
  }
  #pragma unroll
  for (int msk = 1; msk < 32; msk <<= 1){
    float mo = __shfl_xor(m, msk), so = __shfl_xor(s, msk);
    float mn = fmaxf(m, mo);
    s = s * __expf(m - mn) + so * __expf(mo - mn);
    m = mn;
  }
  const float inv = 1.0f / s;

  float acc[16];
  #pragma unroll
  for (int i = 0; i < 16; ++i) acc[i] = 0.f;

  int e = start;
  int r = (e < end) ? ref2seg[e] : 0;
  while (e < end){
    int rn = (e + 1 < end) ? ref2seg[e + 1] : 0;
    float sc = __expf(db[r] - m) * inv;
    const uint4* Ur = (const uint4*)(U + ((size_t)r << 9) + c);
    uint4 u0 = Ur[0], u1 = Ur[1];
    fma8(u0, sc, acc);
    fma8(u1, sc, acc + 8);
    r = rn; ++e;
  }

  float* op = out + (((size_t)(b * NSEG + n)) << 9) + c;
  const float* bp = bo + c;
  #pragma unroll
  for (int i = 0; i < 16; ++i) op[i] = acc[i] + bp[i];
}

extern "C" void kernel_launch(void* const* d_in, const int* in_sizes, int n_in,
                              void* d_out, int out_size, void* d_ws, size_t ws_size,
                              hipStream_t stream) {
  const int*   Q        = (const int*)d_in[0];
  const int*   Qok      = (const int*)d_in[1];
  const int*   refs     = (const int*)d_in[2];
  const int*   okpos    = (const int*)d_in[3];
  const int*   ref2seg  = (const int*)d_in[4];
  const int*   segments = (const int*)d_in[5];
  const float* W        = (const float*)d_in[7];
  const float* bo       = (const float*)d_in[8];
  float* out = (float*)d_out;

  char* ws = (char*)d_ws;
  unsigned short* WT       = (unsigned short*)ws;                  // [0, 1MB)
  float*          dists    = (float*)(ws + (1u<<20));              // 128 KB
  int*            segstart = (int*)(ws + (1u<<20) + (128u<<10));   // ~4 KB
  unsigned short* Rb       = (unsigned short*)(ws + (2u<<20));     // [2MB, 10MB)
  unsigned short* U        = (unsigned short*)(ws + (10u<<20));    // [10MB, 14MB)

  k_wconv <<<(OUTD*DBITS)/256, 256, 0, stream>>>(W, WT);
  k_unpack<<<(R_REF*DB/8)/256, 256, 0, stream>>>(refs, Rb);
  k_dist  <<<(B_Q*R_REF)/4, 256, 0, stream>>>(Q, Qok, refs, okpos, dists);
  k_bounds<<<NSEG/256, 256, 0, stream>>>(segments, segstart);
  k_ugemm <<<dim3(R_REF/64, OUTD/64), 256, 0, stream>>>(Rb, WT, U);
  k_scat  <<<NSEG, 256, 0, stream>>>(dists, ref2seg, segstart, U, bo, out);
}